// Round 2
// baseline (598.472 us; speedup 1.0000x reference)
//
#include <hip/hip_runtime.h>

#define M_DIM 8192
#define N_DIM 4096
#define K_DIM 4096

typedef __attribute__((ext_vector_type(8))) __bf16 bf16x8;
typedef __attribute__((ext_vector_type(16))) float f32x16;
typedef __attribute__((ext_vector_type(8))) unsigned short u16x8;

typedef const __attribute__((address_space(1))) unsigned int gu32_t;
typedef __attribute__((address_space(3))) unsigned int lu32_t;

// fp32 -> bf16 round-to-nearest-even (bit trick; exact for ints <= 256)
static __device__ __forceinline__ unsigned short f2bf(float f) {
    union { float f; unsigned int u; } v; v.f = f;
    unsigned int u = v.u;
    return (unsigned short)((u + 0x7fffu + ((u >> 16) & 1u)) >> 16);
}

#define X_BLOCKS 32768   // (M*K/4) / 256 threads, 1 float4 per thread

// ---------- fused prep: x fp32->bf16 (coalesced) + W int32 [K][N] -> bf16 W^T [N][K] ----------
__global__ __launch_bounds__(256) void prep_kernel(const float* __restrict__ x,
                                                   unsigned short* __restrict__ xb,
                                                   const int* __restrict__ w,
                                                   unsigned short* __restrict__ wt) {
    __shared__ unsigned short t[64][72];   // only used by the W branch
    const int tid = threadIdx.x;
    if (blockIdx.x < X_BLOCKS) {
        // perfectly coalesced: thread g reads float4 #g (16B), writes ushort4 (8B)
        size_t g = (size_t)blockIdx.x * 256 + tid;
        float4 a = ((const float4*)x)[g];
        ushort4 o;
        o.x = f2bf(a.x); o.y = f2bf(a.y); o.z = f2bf(a.z); o.w = f2bf(a.w);
        ((ushort4*)xb)[g] = o;
    } else {
        // 64x64 transpose tile (round-1 proven pattern)
        int bid = blockIdx.x - X_BLOCKS;
        int n0 = (bid & 63) * 64;
        int k0 = (bid >> 6) * 64;
#pragma unroll
        for (int i = 0; i < 16; i++) {
            int idx = tid + i * 256;
            int r = idx >> 6, c = idx & 63;          // r: k-offset, c: n-offset (coalesced)
            int v = w[(size_t)(k0 + r) * N_DIM + n0 + c];
            t[c][r] = f2bf((float)v);                // transposed write
        }
        __syncthreads();
#pragma unroll
        for (int i = 0; i < 2; i++) {
            int slot = tid + i * 256;
            int r = slot >> 3, c = (slot & 7) * 8;
            u16x8 o = *(const u16x8*)&t[r][c];
            *(u16x8*)&wt[(size_t)(n0 + r) * K_DIM + k0 + c] = o;
        }
    }
}

// ---------- GEMM: C[M][N] = A[M][K](bf16) * B^T (B stored [N][K] bf16), * scaler ----------
// 128x128 tile, BK=32, 256 threads = 4 waves in 2x2; each wave 64x64 via 2x2 MFMA 32x32x16.
__global__ __launch_bounds__(256) void gemm_bt_kernel(const unsigned short* __restrict__ A,
                                                      const unsigned short* __restrict__ B,
                                                      const float* __restrict__ scaler,
                                                      float* __restrict__ C) {
    __shared__ unsigned short As[128 * 32];  // [m][k] row-major, 8 KB
    __shared__ unsigned short Bs[128 * 32];  // [n][k] row-major, 8 KB

    const int tid  = threadIdx.x;
    const int m0   = blockIdx.y * 128;
    const int n0   = blockIdx.x * 128;
    const int wave = tid >> 6, lane = tid & 63;
    const int l31  = lane & 31, lh = lane >> 5;   // 32x32 frag: row = l31, k-half = lh
    const int wm   = wave >> 1, wn = wave & 1;

    // staging: 512 chunks of 16B per tile; thread t handles chunks t and t+256
    const int q0 = tid, q1 = tid + 256;
    const unsigned short* ga0 = A + (size_t)(m0 + (q0 >> 2)) * K_DIM + (q0 & 3) * 8;
    const unsigned short* ga1 = A + (size_t)(m0 + (q1 >> 2)) * K_DIM + (q1 & 3) * 8;
    const unsigned short* gb0 = B + (size_t)(n0 + (q0 >> 2)) * K_DIM + (q0 & 3) * 8;
    const unsigned short* gb1 = B + (size_t)(n0 + (q1 >> 2)) * K_DIM + (q1 & 3) * 8;
    unsigned short* la0 = As + q0 * 8;
    unsigned short* la1 = As + q1 * 8;
    unsigned short* lb0 = Bs + q0 * 8;
    unsigned short* lb1 = Bs + q1 * 8;

    f32x16 acc[2][2];
#pragma unroll
    for (int i = 0; i < 2; i++)
#pragma unroll
        for (int j = 0; j < 2; j++)
#pragma unroll
            for (int r = 0; r < 16; r++) acc[i][j][r] = 0.f;

    // A-frag for 32x32x16: lane holds A[m = l31][k = lh*8 + j], contiguous 16B
    const unsigned short* pa = &As[(wm * 64 + l31) * 32 + lh * 8];
    const unsigned short* pb = &Bs[(wn * 64 + l31) * 32 + lh * 8];

    for (int kt = 0; kt < K_DIM / 32; ++kt) {
        __builtin_amdgcn_global_load_lds((gu32_t*)ga0, (lu32_t*)la0, 16, 0, 0);
        __builtin_amdgcn_global_load_lds((gu32_t*)ga1, (lu32_t*)la1, 16, 0, 0);
        __builtin_amdgcn_global_load_lds((gu32_t*)gb0, (lu32_t*)lb0, 16, 0, 0);
        __builtin_amdgcn_global_load_lds((gu32_t*)gb1, (lu32_t*)lb1, 16, 0, 0);
        ga0 += 32; ga1 += 32; gb0 += 32; gb1 += 32;
        __syncthreads();

        bf16x8 af[2][2], bfr[2][2];   // [tile][k-step]
#pragma unroll
        for (int ti = 0; ti < 2; ti++)
#pragma unroll
            for (int ks = 0; ks < 2; ks++) {
                af[ti][ks]  = *(const bf16x8*)(pa + ti * 32 * 32 + ks * 16);
                bfr[ti][ks] = *(const bf16x8*)(pb + ti * 32 * 32 + ks * 16);
            }

#pragma unroll
        for (int ks = 0; ks < 2; ks++)
#pragma unroll
            for (int ti = 0; ti < 2; ti++)
#pragma unroll
                for (int tj = 0; tj < 2; tj++)
                    acc[ti][tj] = __builtin_amdgcn_mfma_f32_32x32x16_bf16(
                        af[ti][ks], bfr[tj][ks], acc[ti][tj], 0, 0, 0);
        __syncthreads();
    }

    const float s = scaler[0];
    // 32x32 C/D layout (m74/m101-verified): col = lane&31, row = (reg&3) + 8*(reg>>2) + 4*(lane>>5)
#pragma unroll
    for (int ti = 0; ti < 2; ti++)
#pragma unroll
        for (int tj = 0; tj < 2; tj++) {
            const int col = n0 + wn * 64 + tj * 32 + l31;
#pragma unroll
            for (int reg = 0; reg < 16; reg++) {
                const int row = m0 + wm * 64 + ti * 32 + (reg & 3) + 8 * (reg >> 2) + 4 * lh;
                C[(size_t)row * N_DIM + col] = acc[ti][tj][reg] * s;
            }
        }
}

extern "C" void kernel_launch(void* const* d_in, const int* in_sizes, int n_in,
                              void* d_out, int out_size, void* d_ws, size_t ws_size,
                              hipStream_t stream) {
    const float* x      = (const float*)d_in[0];
    const float* scaler = (const float*)d_in[1];
    const int*   w      = (const int*)d_in[2];
    float*       out    = (float*)d_out;

    unsigned short* xb = (unsigned short*)d_ws;                 // bf16 x   [M][K], 64 MiB
    unsigned short* wt = xb + (size_t)M_DIM * K_DIM;            // bf16 W^T [N][K], 32 MiB

    prep_kernel<<<X_BLOCKS + (N_DIM / 64) * (K_DIM / 64), 256, 0, stream>>>(x, xb, w, wt);
    gemm_bt_kernel<<<dim3(N_DIM / 128, M_DIM / 128), 256, 0, stream>>>(xb, wt, scaler, out);
}

// Round 4
// 560.799 us; speedup vs baseline: 1.0672x; 1.0672x over previous
//
#include <hip/hip_runtime.h>

#define M_DIM 8192
#define N_DIM 4096
#define K_DIM 4096

typedef __attribute__((ext_vector_type(8))) __bf16 bf16x8;
typedef __attribute__((ext_vector_type(4))) float f32x4;
typedef __attribute__((ext_vector_type(8))) unsigned short u16x8;

typedef const __attribute__((address_space(1))) unsigned int gu32_t;
typedef __attribute__((address_space(3))) unsigned int lu32_t;

// fp32 -> bf16 round-to-nearest-even (bit trick; exact for ints <= 256)
static __device__ __forceinline__ unsigned short f2bf(float f) {
    union { float f; unsigned int u; } v; v.f = f;
    unsigned int u = v.u;
    return (unsigned short)((u + 0x7fffu + ((u >> 16) & 1u)) >> 16);
}

#define X_BLOCKS 32768   // (M*K/4) / 256 threads, 1 float4 per thread

// ---------- fused prep: x fp32->bf16 (coalesced) + W int32 [K][N] -> bf16 W^T [N][K] ----------
__global__ __launch_bounds__(256) void prep_kernel(const float* __restrict__ x,
                                                   unsigned short* __restrict__ xb,
                                                   const int* __restrict__ w,
                                                   unsigned short* __restrict__ wt) {
    __shared__ unsigned short t[64][72];   // only used by the W branch
    const int tid = threadIdx.x;
    if (blockIdx.x < X_BLOCKS) {
        size_t g = (size_t)blockIdx.x * 256 + tid;
        float4 a = ((const float4*)x)[g];
        ushort4 o;
        o.x = f2bf(a.x); o.y = f2bf(a.y); o.z = f2bf(a.z); o.w = f2bf(a.w);
        ((ushort4*)xb)[g] = o;
    } else {
        int bid = blockIdx.x - X_BLOCKS;
        int n0 = (bid & 63) * 64;
        int k0 = (bid >> 6) * 64;
#pragma unroll
        for (int i = 0; i < 16; i++) {
            int idx = tid + i * 256;
            int r = idx >> 6, c = idx & 63;          // r: k-offset, c: n-offset (coalesced)
            int v = w[(size_t)(k0 + r) * N_DIM + n0 + c];
            t[c][r] = f2bf((float)v);                // transposed write
        }
        __syncthreads();
#pragma unroll
        for (int i = 0; i < 2; i++) {
            int slot = tid + i * 256;
            int r = slot >> 3, c = (slot & 7) * 8;
            u16x8 o = *(const u16x8*)&t[r][c];
            *(u16x8*)&wt[(size_t)(n0 + r) * K_DIM + k0 + c] = o;
        }
    }
}

// Row-dependent slot swizzle: global chunk (row m, k-chunk kc) lives at LDS slot
// m*4 + (kc ^ f(m)), f(m) = (m + (m>>2)) & 3.
//  - f(m+16) == f(m)  -> one fragment pointer serves all mi tiles
//  - XOR is self-inverse -> read slot = quad ^ f(m)
//  - spreads each 16-lane b128 phase across all 8 bank-quad-groups (was 2)
static __device__ __forceinline__ int swz(int m) { return (m + (m >> 2)) & 3; }

// ---------- GEMM: C[M][N] = A[M][K](bf16) * B^T (B stored [N][K] bf16), * scaler ----------
// 128x128 tile, BK=32, 256 threads = 4 waves in 2x2, each wave 64x64 via 4x4 MFMA 16x16x32.
// Swizzle applied on the GLOBAL address side (per-lane allowed), since global_load_lds's
// LDS destination is fixed at wave-base + lane*16 and cannot scatter.
__global__ __launch_bounds__(256) void gemm_bt_kernel(const unsigned short* __restrict__ A,
                                                      const unsigned short* __restrict__ B,
                                                      const float* __restrict__ scaler,
                                                      float* __restrict__ C) {
    __shared__ unsigned short As[128 * 32];  // 8 KB, swizzled
    __shared__ unsigned short Bs[128 * 32];  // 8 KB, swizzled

    const int tid  = threadIdx.x;
    const int m0   = blockIdx.y * 128;
    const int n0   = blockIdx.x * 128;
    const int wave = tid >> 6, lane = tid & 63;
    const int quad = lane >> 4, lr = lane & 15;
    const int wm   = wave >> 1, wn = wave & 1;

    // staging: thread t fills LDS slot q from global chunk kc = (q&3) ^ f(q>>2)
    const int q0 = tid, q1 = tid + 256;
    const int r0 = q0 >> 2, kc0 = (q0 & 3) ^ swz(r0);
    const int r1 = q1 >> 2, kc1 = (q1 & 3) ^ swz(r1);
    const unsigned short* ga0 = A + (size_t)(m0 + r0) * K_DIM + kc0 * 8;
    const unsigned short* ga1 = A + (size_t)(m0 + r1) * K_DIM + kc1 * 8;
    const unsigned short* gb0 = B + (size_t)(n0 + r0) * K_DIM + kc0 * 8;
    const unsigned short* gb1 = B + (size_t)(n0 + r1) * K_DIM + kc1 * 8;
    unsigned short* la0 = As + q0 * 8;
    unsigned short* la1 = As + q1 * 8;
    unsigned short* lb0 = Bs + q0 * 8;
    unsigned short* lb1 = Bs + q1 * 8;

    f32x4 acc[4][4];
#pragma unroll
    for (int i = 0; i < 4; i++)
#pragma unroll
        for (int j = 0; j < 4; j++) acc[i][j] = (f32x4){0.f, 0.f, 0.f, 0.f};

    // fragment read: row m_loc = wm*64 + mi*16 + lr, k-chunk = quad,
    // slot = quad ^ f(m_loc); f invariant under +16 so one pointer serves all mi
    const int swa = quad ^ swz(wm * 64 + lr);
    const int swb = quad ^ swz(wn * 64 + lr);
    const unsigned short* pa = &As[((wm * 64 + lr) * 4 + swa) * 8];
    const unsigned short* pb = &Bs[((wn * 64 + lr) * 4 + swb) * 8];

    for (int kt = 0; kt < K_DIM / 32; ++kt) {
        __builtin_amdgcn_global_load_lds((gu32_t*)ga0, (lu32_t*)la0, 16, 0, 0);
        __builtin_amdgcn_global_load_lds((gu32_t*)ga1, (lu32_t*)la1, 16, 0, 0);
        __builtin_amdgcn_global_load_lds((gu32_t*)gb0, (lu32_t*)lb0, 16, 0, 0);
        __builtin_amdgcn_global_load_lds((gu32_t*)gb1, (lu32_t*)lb1, 16, 0, 0);
        ga0 += 32; ga1 += 32; gb0 += 32; gb1 += 32;
        __syncthreads();

        bf16x8 af[4], bf[4];
#pragma unroll
        for (int mi = 0; mi < 4; mi++) af[mi] = *(const bf16x8*)(pa + mi * 512);
#pragma unroll
        for (int ni = 0; ni < 4; ni++) bf[ni] = *(const bf16x8*)(pb + ni * 512);

#pragma unroll
        for (int mi = 0; mi < 4; mi++)
#pragma unroll
            for (int ni = 0; ni < 4; ni++)
                acc[mi][ni] = __builtin_amdgcn_mfma_f32_16x16x32_bf16(
                    af[mi], bf[ni], acc[mi][ni], 0, 0, 0);
        __syncthreads();
    }

    const float s = scaler[0];
    // C/D layout (m89-verified): col = lane&15, row = (lane>>4)*4 + reg
#pragma unroll
    for (int mi = 0; mi < 4; mi++)
#pragma unroll
        for (int ni = 0; ni < 4; ni++) {
            const int row = m0 + wm * 64 + mi * 16 + quad * 4;
            const int col = n0 + wn * 64 + ni * 16 + lr;
            float* cp = C + (size_t)row * N_DIM + col;
#pragma unroll
            for (int r = 0; r < 4; r++)
                cp[(size_t)r * N_DIM] = acc[mi][ni][r] * s;
        }
}

extern "C" void kernel_launch(void* const* d_in, const int* in_sizes, int n_in,
                              void* d_out, int out_size, void* d_ws, size_t ws_size,
                              hipStream_t stream) {
    const float* x      = (const float*)d_in[0];
    const float* scaler = (const float*)d_in[1];
    const int*   w      = (const int*)d_in[2];
    float*       out    = (float*)d_out;

    unsigned short* xb = (unsigned short*)d_ws;                 // bf16 x   [M][K], 64 MiB
    unsigned short* wt = xb + (size_t)M_DIM * K_DIM;            // bf16 W^T [N][K], 32 MiB

    prep_kernel<<<X_BLOCKS + (N_DIM / 64) * (K_DIM / 64), 256, 0, stream>>>(x, xb, w, wt);
    gemm_bt_kernel<<<dim3(N_DIM / 128, M_DIM / 128), 256, 0, stream>>>(xb, wt, scaler, out);
}